// Round 8
// baseline (15944.707 us; speedup 1.0000x reference)
//
#include <hip/hip_runtime.h>
#include <hip/hip_fp16.h>

// HMM forward (CgpHmmLayer): B=64, T=4096, S=305.
// A as f16 ROW-PAIRS -> 100 v2f16 regs/thread (~135 total < 256 cap, no spill),
// v_dot2_f32_f16 accumulate in f32.
// Round 7 lesson: 1-step-delayed scale by 1/tot_{t-2} is a MARGINALLY STABLE
// oscillator (x_t = logc + x_{t-1} - x_{t-2}, roots on unit circle) -> random
// walk in log magnitude -> f16 flush-to-zero -> tot=0 -> NaN. Fix: DAMPED scale
// rsqrt(tot_{t-2}) (x_t = logc + x_{t-1} - 0.5 x_{t-2}, |roots|=0.707, std ~2
// log2 units). Any wave-uniform scale telescopes exactly:
//   ll = sum log2(scale_applied) + log2(sum va_final).
// Per step: s1: scale va, cvt alpha pairs (readlane x2 + cvt_pkrtz), 100 dot2,
// 5 ds_add_f32 into buf[t&1]; ONE barrier; s2: gather own col, re-zero for t+2,
// *emission, wave-reduce sum -> sN[t&1][w] (consumed at t+2).
// Init-softmax normalizer folded into final -log2(Z_I).

constexpr int NS   = 305;
constexpr int NSP  = 320;
constexpr int NT   = 4096;
constexpr int NW   = 8;
constexpr int RPW  = 40;   // rows per wave
constexpr int NPAIR = 20;  // row-pairs per wave

typedef _Float16 h2 __attribute__((ext_vector_type(2)));

__device__ __forceinline__ float fdot2f(h2 a, h2 b, float c) {
#if __has_builtin(__builtin_amdgcn_fdot2)
    return __builtin_amdgcn_fdot2(a, b, c, false);
#else
    return c + (float)a[0] * (float)b[0] + (float)a[1] * (float)b[1];
#endif
}

__device__ __forceinline__ float wave_sum(float v) {
    #pragma unroll
    for (int off = 32; off; off >>= 1) v += __shfl_xor(v, off, 64);
    return v;
}

#define TWENTY(X) X(0) X(1) X(2) X(3) X(4) X(5) X(6) X(7) X(8) X(9) \
  X(10) X(11) X(12) X(13) X(14) X(15) X(16) X(17) X(18) X(19)

__global__ __launch_bounds__(64)
void prep_Ah(const float* __restrict__ transk, unsigned* __restrict__ wsH)
{
    const int p = blockIdx.x;     // row pair 0..159
    const int l = threadIdx.x;    // lane 0..63
    const int r0 = 2 * p, r1 = 2 * p + 1;
    float e0[5], e1[5];
    float s0 = 0.f, s1 = 0.f;
    #pragma unroll
    for (int k = 0; k < 5; ++k) {
        const int c = l + 64 * k;
        e0[k] = (r0 < NS && c < NS) ? __expf(transk[r0 * NS + c]) : 0.f;
        e1[k] = (r1 < NS && c < NS) ? __expf(transk[r1 * NS + c]) : 0.f;
        s0 += e0[k]; s1 += e1[k];
    }
    s0 = wave_sum(s0); s1 = wave_sum(s1);
    const float i0 = (r0 < NS) ? 1.f / s0 : 0.f;
    const float i1 = (r1 < NS) ? 1.f / s1 : 0.f;
    #pragma unroll
    for (int k = 0; k < 5; ++k) {
        unsigned h0 = __half_as_ushort(__float2half(e0[k] * i0));
        unsigned h1 = __half_as_ushort(__float2half(e1[k] * i1));
        wsH[p * NSP + l + 64 * k] = h0 | (h1 << 16);
    }
}

__global__ __launch_bounds__(512, 2)
void hmm_fwd(const float* __restrict__ inputs,
             const float* __restrict__ initk,
             const float* __restrict__ emisk,
             const unsigned* __restrict__ wsH,
             float* __restrict__ out)
{
    __shared__ float sBm[4 * NSP];
    __shared__ float sI[NSP];
    __shared__ float buf[2 * NSP];          // ping-pong ds_add accumulators
    __shared__ __align__(16) float sN[16];  // ping-pong 8+8 wave sums (float4-read)
    __shared__ unsigned char sObs[NT];

    const int tid = threadIdx.x;
    const int w   = tid >> 6;
    const int l   = tid & 63;
    const int b   = blockIdx.x;

    // zero phase
    for (int i = tid; i < 4 * NSP; i += 512) sBm[i] = 0.f;
    if (tid < NSP) sI[tid] = 0.f;
    for (int i = tid; i < 2 * NSP; i += 512) buf[i] = 0.f;
    __syncthreads();

    // decode one-hot observations (coalesced float4)
    const float4* oh = (const float4*)(inputs + (size_t)b * NT * 4);
    #pragma unroll
    for (int i = 0; i < NT / 512; ++i) {
        int t = tid + i * 512;
        float4 v = oh[t];
        sObs[t] = (unsigned char)(int)(v.y + 2.f * v.z + 3.f * v.w + 0.5f);
    }

    // emission softmax over 4; init vector exp (normalizer folded at end)
    if (tid < NS) {
        float4 ek = ((const float4*)emisk)[tid];
        float e0 = __expf(ek.x), e1 = __expf(ek.y), e2 = __expf(ek.z), e3 = __expf(ek.w);
        float inv = 1.f / (e0 + e1 + e2 + e3);
        sBm[0 * NSP + tid] = e0 * inv;
        sBm[1 * NSP + tid] = e1 * inv;
        sBm[2 * NSP + tid] = e2 * inv;
        sBm[3 * NSP + tid] = e3 * inv;
        sI[tid] = __expf(initk[tid]);
    }
    __syncthreads();

    // log2(Z_I)
    float v0 = (tid < NSP) ? sI[tid] : 0.f;
    v0 = wave_sum(v0);
    if (l == 0) sN[w] = v0;
    __syncthreads();
    float lz2;
    {
        const float4* s4 = (const float4*)sN;
        float4 p0 = s4[0], p1 = s4[1];
        lz2 = __builtin_amdgcn_logf(((p0.x + p0.y) + (p0.z + p0.w)) +
                                    ((p1.x + p1.y) + (p1.z + p1.w)));
    }
    __syncthreads();   // sN reusable

    // ---- A-slice: 100 named v2f16 (as uint), loaded once, pinned ----
    const unsigned* wh = wsH + (size_t)(w * NPAIR) * NSP + l;
#define DECLA(J) unsigned au##J##_0, au##J##_1, au##J##_2, au##J##_3, au##J##_4;
    TWENTY(DECLA)
#undef DECLA
#define LOADA(J) \
    au##J##_0 = wh[J * NSP];        \
    au##J##_1 = wh[J * NSP + 64];   \
    au##J##_2 = wh[J * NSP + 128];  \
    au##J##_3 = wh[J * NSP + 192];  \
    au##J##_4 = wh[J * NSP + 256];
    TWENTY(LOADA)
#undef LOADA
#define PINA(J) asm volatile("" : "+v"(au##J##_0), "+v"(au##J##_1), \
    "+v"(au##J##_2), "+v"(au##J##_3), "+v"(au##J##_4));
    TWENTY(PINA)
#undef PINA

    // matvec macro: rows (40w+2J, 40w+2J+1) broadcast from lanes 2J, 2J+1
#define DOTJ(J) { \
    unsigned s0_ = __builtin_amdgcn_readlane(__float_as_uint(va), 2 * J);     \
    unsigned s1_ = __builtin_amdgcn_readlane(__float_as_uint(va), 2 * J + 1); \
    h2 sa_ = __builtin_bit_cast(h2, \
        __builtin_amdgcn_cvt_pkrtz(__uint_as_float(s0_), __uint_as_float(s1_))); \
    acc0 = fdot2f(sa_, __builtin_bit_cast(h2, au##J##_0), acc0); \
    acc1 = fdot2f(sa_, __builtin_bit_cast(h2, au##J##_1), acc1); \
    acc2 = fdot2f(sa_, __builtin_bit_cast(h2, au##J##_2), acc2); \
    acc3 = fdot2f(sa_, __builtin_bit_cast(h2, au##J##_3), acc3); \
    acc4 = fdot2f(sa_, __builtin_bit_cast(h2, au##J##_4), acc4); }

    // ---- t = 0: va = expI * E0 (unnormalized); record wave sums in slot 0 ----
    float va = 0.f;
    {
        int o0 = sObs[0];
        int col = w * RPW + l;
        if (l < RPW) va = sI[col] * sBm[o0 * NSP + col];
    }
    { float v = wave_sum(va); if (l == 0) sN[0 * 8 + w] = v; }
    float ll2 = 0.f;
    __syncthreads();   // b(0)

    // ---- peeled t = 1 (no stale sum yet; no scale) ----
    {
        float acc0 = 0.f, acc1 = 0.f, acc2 = 0.f, acc3 = 0.f, acc4 = 0.f;
        TWENTY(DOTJ)
        atomicAdd(&buf[NSP + l      ], acc0);
        atomicAdd(&buf[NSP + l +  64], acc1);
        atomicAdd(&buf[NSP + l + 128], acc2);
        atomicAdd(&buf[NSP + l + 192], acc3);
        atomicAdd(&buf[NSP + l + 256], acc4);
        __syncthreads();   // b(1)
        const int o = sObs[1];
        if (l < RPW) {
            const int col = w * RPW + l;
            float g = buf[NSP + col];
            buf[NSP + col] = 0.f;
            va = g * sBm[o * NSP + col];
        } else va = 0.f;
        float v = wave_sum(va);
        if (l == 0) sN[8 + w] = v;
    }

    // ---- main loop: one barrier/step, DAMPED two-step-stale normalization ----
    #pragma unroll 2
    for (int t = 2; t < NT; ++t) {
        const int sl = (t & 1) * NSP;
        const int sn = (t & 1) * 8;
        {   // stale sum from step t-2; damped scale rsqrt(tot) (exact telescoping:
            // applied scale is logged as 0.5*log2(tot))
            const float4* s4 = (const float4*)(sN + sn);
            float4 p0 = s4[0], p1 = s4[1];
            float tot = ((p0.x + p0.y) + (p0.z + p0.w)) + ((p1.x + p1.y) + (p1.z + p1.w));
            tot = fmaxf(tot, 1e-30f);
            ll2 += 0.5f * __builtin_amdgcn_logf(tot);
            va  *= __frsqrt_rn(tot);
        }
        float acc0 = 0.f, acc1 = 0.f, acc2 = 0.f, acc3 = 0.f, acc4 = 0.f;
        TWENTY(DOTJ)
        atomicAdd(&buf[sl + l      ], acc0);
        atomicAdd(&buf[sl + l +  64], acc1);
        atomicAdd(&buf[sl + l + 128], acc2);
        atomicAdd(&buf[sl + l + 192], acc3);
        atomicAdd(&buf[sl + l + 256], acc4);
        __syncthreads();   // b(t)
        const int o = sObs[t];
        if (l < RPW) {
            const int col = w * RPW + l;
            float g = buf[sl + col];
            buf[sl + col] = 0.f;          // ready for step t+2
            va = g * sBm[o * NSP + col];
        } else va = 0.f;
        float v = wave_sum(va);
        if (l == 0) sN[sn + w] = v;       // consumed at step t+2
    }

    // ---- final: last measured sum enters in full ----
    __syncthreads();
    {
        const float4* s4 = (const float4*)(sN + ((NT - 1) & 1) * 8);
        float4 p0 = s4[0], p1 = s4[1];
        float tot = ((p0.x + p0.y) + (p0.z + p0.w)) + ((p1.x + p1.y) + (p1.z + p1.w));
        tot = fmaxf(tot, 1e-30f);
        ll2 += __builtin_amdgcn_logf(tot);
    }
    if (tid == 0) out[b] = (ll2 - lz2) * 0.6931471805599453f;
#undef DOTJ
}

extern "C" void kernel_launch(void* const* d_in, const int* in_sizes, int n_in,
                              void* d_out, int out_size, void* d_ws, size_t ws_size,
                              hipStream_t stream) {
    const float* inputs = (const float*)d_in[0];
    const float* initk  = (const float*)d_in[1];
    const float* transk = (const float*)d_in[2];
    const float* emisk  = (const float*)d_in[3];
    unsigned* wsH = (unsigned*)d_ws;   // 160*320*4 = 204800 bytes

    hipLaunchKernelGGL(prep_Ah, dim3(NSP / 2), dim3(64), 0, stream, transk, wsH);
    hipLaunchKernelGGL(hmm_fwd, dim3(64), dim3(512), 0, stream,
                       inputs, initk, emisk, wsH, (float*)d_out);
}